// Round 12
// baseline (1294.555 us; speedup 1.0000x reference)
//
#include <hip/hip_runtime.h>
#include <math.h>

namespace {
constexpr int LSEQ = 32;
constexpr int CDIM = 64;
constexpr int HDIM = 128;
constexpr int FDIM = 32;
constexpr float TWO_PI = 6.28318530717958647692f;

__device__ __forceinline__ float sigf(float x) { return 1.0f / (1.0f + __expf(-x)); }
__device__ __forceinline__ float tanh_fast(float x) { return 1.0f - 2.0f / (__expf(2.0f * x) + 1.0f); }
}

// S=2 seqs/block, 512 blocks -> 2 co-resident blocks/CU, 256 threads each.
// Mechanism: two independent barrier domains per CU (block A computes while
// block B drains a barrier). 256-thr blocks lift the hipcc VGPR cap
// (65536/blockDim law: 256thr -> 256 VGPR) so mogrify weights live in
// registers (qreg/rreg); LDS ~15 KB guarantees co-residency (R8 lesson).
__global__ __launch_bounds__(256, 1)
void sfm_lstm_r12(const float* __restrict__ x,
                  const float* __restrict__ Q, const float* __restrict__ R,
                  const float* __restrict__ Wi, const float* __restrict__ bi,
                  const float* __restrict__ Wg, const float* __restrict__ bg,
                  const float* __restrict__ Wste, const float* __restrict__ bste,
                  const float* __restrict__ Wfre, const float* __restrict__ bfre,
                  const float* __restrict__ Wom, const float* __restrict__ bom,
                  const float* __restrict__ Wo, const float* __restrict__ bo,
                  const float* __restrict__ Wa, const float* __restrict__ ba,
                  const float* __restrict__ Wout, const float* __restrict__ bout,
                  float* __restrict__ out)
{
    const int t = threadIdx.x;
    const int blk = blockIdx.x;

    // soh[320][2]: rows 0..63 = xt, 64..191 = h, 192..319 = c_t  ([dim][seq])
    __shared__ __align__(8) float soh[320][2];
    __shared__ __align__(8) float sit[HDIM][2];
    __shared__ __align__(8) float schat[HDIM][2];
    __shared__ __align__(8) float sfste[HDIM][2];
    __shared__ __align__(8) float sffre[FDIM][2];
    __shared__ __align__(8) float scosv[FDIM][2];
    __shared__ __align__(8) float ssinv[FDIM][2];
    __shared__ __align__(16) float spart[2048];        // 8 KB partials
    __shared__ float swa[FDIM];

    if (t < FDIM) swa[t] = Wa[t];
    soh[64 + (t >> 1)][t & 1] = 0.0f;                  // h = 0 (256 = 128x2)

    // state role: (row r7, seq sA), full F per thread
    const int r7 = t & 127, sA = t >> 7;
    float re[FDIM], im[FDIM];
    #pragma unroll
    for (int f = 0; f < FDIM; ++f) { re[f] = 0.0f; im[f] = 0.0f; }

    // ---- mogrify roles + register-cached weight slices ----
    const int mc = t & 63,  mksx = t >> 6;             // x-phase: col mc, 4 k-slices of 32
    const int mj = t & 127, mksh = t >> 7;             // h-phase: col mj, 2 k-slices of 32
    float qreg[32], rreg[32];
    #pragma unroll
    for (int kk = 0; kk < 32; ++kk) qreg[kk] = Q[(mksx * 32 + kk) * CDIM + mc];
    #pragma unroll
    for (int kk = 0; kk < 32; ++kk) rreg[kk] = R[(mksh * 32 + kk) * HDIM + mj];

    // ---- gate PARTIAL role (t<224): group grp owns cols 4grp..4grp+3, k-half kh
    const int grp = t >> 1, kh = t & 1;
    const int gcol0 = 4 * grp;                         // 0..444
    const float* wPt = Wi; int strP = HDIM;
    if      (gcol0 < 128) { wPt = Wi   + gcol0;         strP = HDIM; }
    else if (gcol0 < 256) { wPt = Wg   + (gcol0 - 128); strP = HDIM; }
    else if (gcol0 < 384) { wPt = Wste + (gcol0 - 256); strP = HDIM; }
    else if (gcol0 < 416) { wPt = Wfre + (gcol0 - 384); strP = FDIM; }
    else                  { wPt = Wom  + (gcol0 - 416); strP = FDIM; }
    wPt += (size_t)(96 * kh) * strP;

    // ---- gate REDUCE role (t<224): cols c0, c0+1 where c0 = 4*(t>>1)+2*(t&1)
    const int rc0 = 4 * (t >> 1) + 2 * (t & 1);        // 0..446
    const float* bG = bi; int reg = -1, rcl = 0;
    if      (rc0 < 128) { bG = bi;   rcl = rc0;       reg = 0; }
    else if (rc0 < 256) { bG = bg;   rcl = rc0 - 128; reg = 1; }
    else if (rc0 < 384) { bG = bste; rcl = rc0 - 256; reg = 2; }
    else if (rc0 < 416) { bG = bfre; rcl = rc0 - 384; reg = 3; }
    else if (rc0 < 448) { bG = bom;  rcl = rc0 - 416; reg = 4; }
    const float gb0 = (t < 224) ? bG[rcl] : 0.0f;
    const float gb1 = (t < 224) ? bG[rcl + 1] : 0.0f;

    // ---- out roles: 32 col-groups x 8 k-slices of 40
    const int og = t & 31, oks = t >> 5;
    const float* woPt = Wo + 4 * og + (size_t)(40 * oks) * HDIM;
    const float bo_r = bo[t >> 1];                     // out-reduce col = t>>1

    const float ba0 = ba[0];
    const float* xbase = x + (size_t)blk * 2 * LSEQ * CDIM;
    const int pl = t - 224;                            // prefetch lane (t>=224): 0..31

    // prologue: x(ts=0): 128 values
    if (t < 128) soh[t & 63][t >> 6] = xbase[((t >> 6) * LSEQ) * CDIM + (t & 63)];
    __syncthreads();

    for (int ts = 0; ts < LSEQ; ++ts) {
        // ---- mogrify x,h,x,h,x (weights in registers) ----
        #pragma unroll
        for (int m = 0; m < 5; ++m) {
            if ((m & 1) == 0) {
                // xt = 2*sig(h @ Q) * xt : 64 cols x 4 k-slices of 32
                const int k0 = mksx * 32;
                float a0 = 0.f, a1 = 0.f;
                #pragma unroll
                for (int kk = 0; kk < 32; ++kk) {
                    const float qv = qreg[kk];
                    const float2 h2 = *(const float2*)&soh[64 + k0 + kk][0];
                    a0 += qv * h2.x; a1 += qv * h2.y;
                }
                *(float2*)&spart[mksx * 128 + mc * 2] = make_float2(a0, a1);
                __syncthreads();
                if (t < 128) {
                    const float v = spart[t] + spart[128 + t] + spart[256 + t] + spart[384 + t];
                    soh[t >> 1][t & 1] = 2.0f * sigf(v) * soh[t >> 1][t & 1];
                }
                __syncthreads();
            } else {
                // h = 2*sig(x @ R) * h : 128 cols x 2 k-slices of 32
                const int k0 = mksh * 32;
                float a0 = 0.f, a1 = 0.f;
                #pragma unroll
                for (int kk = 0; kk < 32; ++kk) {
                    const float rv = rreg[kk];
                    const float2 x2 = *(const float2*)&soh[k0 + kk][0];
                    a0 += rv * x2.x; a1 += rv * x2.y;
                }
                *(float2*)&spart[mksh * 256 + mj * 2] = make_float2(a0, a1);
                __syncthreads();
                {
                    const float v = spart[t] + spart[256 + t];
                    soh[64 + (t >> 1)][t & 1] = 2.0f * sigf(v) * soh[64 + (t >> 1)][t & 1];
                }
                __syncthreads();
            }
        }

        // ---- gate partials (t<224): 96 float4 weight loads, 8 FMA each ----
        float xn00 = 0.f, xn01 = 0.f, xn10 = 0.f, xn11 = 0.f;
        if (t < 224) {
            float a00 = 0.f, a01 = 0.f;                // col0 x seq0/1
            float a10 = 0.f, a11 = 0.f;
            float a20 = 0.f, a21 = 0.f;
            float a30 = 0.f, a31 = 0.f;
            const float* wp = wPt;
            const int kb = 96 * kh;
            #pragma unroll 8
            for (int kk = 0; kk < 96; ++kk) {
                const float4 w4 = *(const float4*)wp; wp += strP;
                const float2 i2 = *(const float2*)&soh[kb + kk][0];
                a00 += w4.x * i2.x; a01 += w4.x * i2.y;
                a10 += w4.y * i2.x; a11 += w4.y * i2.y;
                a20 += w4.z * i2.x; a21 += w4.z * i2.y;
                a30 += w4.w * i2.x; a31 += w4.w * i2.y;
            }
            float* sp = &spart[(kh * 112 + grp) * 8];
            *(float4*)(sp)     = make_float4(a00, a01, a10, a11);
            *(float4*)(sp + 4) = make_float4(a20, a21, a30, a31);
        } else if (ts + 1 < LSEQ) {
            // t>=224: prefetch x(ts+1): 4 values each (cols 2*pl, 2*pl+1 x 2 seqs)
            xn00 = xbase[(ts + 1) * CDIM + 2 * pl];
            xn01 = xbase[(ts + 1) * CDIM + 2 * pl + 1];
            xn10 = xbase[(LSEQ + ts + 1) * CDIM + 2 * pl];
            xn11 = xbase[(LSEQ + ts + 1) * CDIM + 2 * pl + 1];
        }
        __syncthreads();

        // ---- gate reduce (t<224): cols rc0, rc0+1 (4 values: 2 cols x 2 seqs) ----
        if (t < 224) {
            const int rgrp = t >> 1, hi = t & 1;
            const float4 p0 = *(const float4*)&spart[rgrp * 8 + hi * 4];
            const float4 p1 = *(const float4*)&spart[(112 + rgrp) * 8 + hi * 4];
            float v00 = p0.x + p1.x + gb0;             // col rc0, seq0
            float v01 = p0.y + p1.y + gb0;             // col rc0, seq1
            float v10 = p0.z + p1.z + gb1;             // col rc0+1, seq0
            float v11 = p0.w + p1.w + gb1;
            if (reg == 4) {
                const float o00 = TWO_PI * sigf(v00), o01 = TWO_PI * sigf(v01);
                const float o10 = TWO_PI * sigf(v10), o11 = TWO_PI * sigf(v11);
                *(float2*)&scosv[rcl][0]     = make_float2(__cosf(o00), __cosf(o01));
                *(float2*)&ssinv[rcl][0]     = make_float2(__sinf(o00), __sinf(o01));
                *(float2*)&scosv[rcl + 1][0] = make_float2(__cosf(o10), __cosf(o11));
                *(float2*)&ssinv[rcl + 1][0] = make_float2(__sinf(o10), __sinf(o11));
            } else {
                float* d = (reg == 0) ? &sit[0][0] : (reg == 1) ? &schat[0][0]
                         : (reg == 2) ? &sfste[0][0] : &sffre[0][0];
                *(float2*)&d[rcl * 2]       = make_float2(sigf(v00), sigf(v01));
                *(float2*)&d[(rcl + 1) * 2] = make_float2(sigf(v10), sigf(v11));
            }
        }
        __syncthreads();

        // ---- complex state + amplitude @ Wa -> c_t : (row,seq)/thread ----
        {
            const float ic = sit[r7][sA] * schat[r7][sA];
            const float fs = sfste[r7][sA];
            float acc = 0.f;
            #pragma unroll
            for (int f = 0; f < FDIM; ++f) {
                const float ft = fs * sffre[f][sA];
                const float cv = scosv[f][sA], sv = ssinv[f][sA];
                re[f] = ft * re[f] + ic * cv;
                im[f] = ft * im[f] + ic * sv;
                acc += sqrtf(re[f] * re[f] + im[f] * im[f]) * swa[f];
            }
            soh[192 + r7][sA] = tanh_fast(acc + ba0);
        }
        __syncthreads();

        // ---- out partials: 40 float4 Wo loads, 8 FMA each ----
        {
            float a00 = 0.f, a01 = 0.f;
            float a10 = 0.f, a11 = 0.f;
            float a20 = 0.f, a21 = 0.f;
            float a30 = 0.f, a31 = 0.f;
            const float* wp = woPt;
            const int kb = 40 * oks;
            #pragma unroll 8
            for (int kk = 0; kk < 40; ++kk) {
                const float4 w4 = *(const float4*)wp; wp += HDIM;
                const float2 i2 = *(const float2*)&soh[kb + kk][0];
                a00 += w4.x * i2.x; a01 += w4.x * i2.y;
                a10 += w4.y * i2.x; a11 += w4.y * i2.y;
                a20 += w4.z * i2.x; a21 += w4.z * i2.y;
                a30 += w4.w * i2.x; a31 += w4.w * i2.y;
            }
            float* sp = &spart[oks * 256 + og * 8];
            *(float4*)(sp)     = make_float4(a00, a01, a10, a11);
            *(float4*)(sp + 4) = make_float4(a20, a21, a30, a31);
        }
        __syncthreads();

        // ---- out reduce (all 256: col=t>>1, seq=t&1) + x commit (t>=224) ----
        {
            float v = 0.f;
            #pragma unroll
            for (int i = 0; i < 8; ++i) v += spart[i * 256 + t];
            const float o = sigf(v + bo_r);
            soh[64 + (t >> 1)][t & 1] = o * tanh_fast(soh[192 + (t >> 1)][t & 1]);
            if (t >= 224 && ts + 1 < LSEQ) {
                soh[2 * pl][0]     = xn00;
                soh[2 * pl + 1][0] = xn01;
                soh[2 * pl][1]     = xn10;
                soh[2 * pl + 1][1] = xn11;
            }
        }
        __syncthreads();
    }

    // ---- out = h_last @ Wout + bout, one wave per sequence ----
    if (t < 128) {
        const int w = t >> 6, l = t & 63;
        float p = soh[64 + l][w] * Wout[l] + soh[128 + l][w] * Wout[64 + l];
        #pragma unroll
        for (int off = 32; off > 0; off >>= 1) p += __shfl_xor(p, off);
        if (l == 0) out[blk * 2 + w] = p + bout[0];
    }
}

extern "C" void kernel_launch(void* const* d_in, const int* in_sizes, int n_in,
                              void* d_out, int out_size, void* d_ws, size_t ws_size,
                              hipStream_t stream) {
    const float* x    = (const float*)d_in[0];
    const float* Q    = (const float*)d_in[1];
    const float* R    = (const float*)d_in[2];
    const float* Wi   = (const float*)d_in[3];
    const float* bi   = (const float*)d_in[4];
    const float* Wg   = (const float*)d_in[5];
    const float* bg   = (const float*)d_in[6];
    const float* Wste = (const float*)d_in[7];
    const float* bste = (const float*)d_in[8];
    const float* Wfre = (const float*)d_in[9];
    const float* bfre = (const float*)d_in[10];
    const float* Wom  = (const float*)d_in[11];
    const float* bom  = (const float*)d_in[12];
    const float* Wo   = (const float*)d_in[13];
    const float* bo   = (const float*)d_in[14];
    const float* Wa   = (const float*)d_in[15];
    const float* ba   = (const float*)d_in[16];
    const float* Wout = (const float*)d_in[17];
    const float* bout = (const float*)d_in[18];
    float* out = (float*)d_out;

    sfm_lstm_r12<<<dim3(512), dim3(256), 0, stream>>>(
        x, Q, R, Wi, bi, Wg, bg, Wste, bste, Wfre, bfre, Wom, bom,
        Wo, bo, Wa, ba, Wout, bout, out);
}

// Round 13
// 376.708 us; speedup vs baseline: 3.4365x; 3.4365x over previous
//
#include <hip/hip_runtime.h>
#include <math.h>

namespace {
constexpr int LSEQ = 32;
constexpr int CDIM = 64;
constexpr int HDIM = 128;
constexpr int FDIM = 32;
constexpr float TWO_PI = 6.28318530717958647692f;

typedef float fv2 __attribute__((ext_vector_type(2)));
typedef float fv4 __attribute__((ext_vector_type(4)));

__device__ __forceinline__ float sigf(float x) { return 1.0f / (1.0f + __expf(-x)); }
__device__ __forceinline__ float tanh_fast(float x) { return 1.0f - 2.0f / (__expf(2.0f * x) + 1.0f); }
}

// S=4 seqs/block, 256 blocks (1/CU), 512 threads. R9 frame (384us) with all
// seq-pair accumulations packed as ext_vector float2 -> v_pk_fma_f32 (VOP3P):
// gates 16->8 ops/iter, out 16->8, mogrify 4->2, state re/im packed by f-pair.
// sffre/scos/ssin flipped to seq-major [4][F] for contiguous (f,f+1) reads.
__global__ __launch_bounds__(512, 1)
void sfm_lstm_r13(const float* __restrict__ x,
                  const float* __restrict__ Q, const float* __restrict__ R,
                  const float* __restrict__ Wi, const float* __restrict__ bi,
                  const float* __restrict__ Wg, const float* __restrict__ bg,
                  const float* __restrict__ Wste, const float* __restrict__ bste,
                  const float* __restrict__ Wfre, const float* __restrict__ bfre,
                  const float* __restrict__ Wom, const float* __restrict__ bom,
                  const float* __restrict__ Wo, const float* __restrict__ bo,
                  const float* __restrict__ Wa, const float* __restrict__ ba,
                  const float* __restrict__ Wout, const float* __restrict__ bout,
                  float* __restrict__ out)
{
    const int t = threadIdx.x;
    const int blk = blockIdx.x;

    __shared__ float sQ[HDIM * CDIM];                  // Q[k][c]  32 KB
    __shared__ float sR[CDIM * HDIM];                  // R[k][j]  32 KB
    // soh[320][4]: rows 0..63 = xt, 64..191 = h, 192..319 = c_t  ([dim][seq])
    __shared__ __align__(16) float soh[320][4];
    __shared__ __align__(16) float sit[HDIM][4];
    __shared__ __align__(16) float schat[HDIM][4];
    __shared__ __align__(16) float sfste[HDIM][4];
    __shared__ __align__(16) float sffre[4][FDIM];     // seq-major for fv2 reads
    __shared__ __align__(16) float scosv[4][FDIM];
    __shared__ __align__(16) float ssinv[4][FDIM];
    __shared__ __align__(16) float spart[8192];        // 32 KB partials
    __shared__ float swa[FDIM];

    #pragma unroll
    for (int i = 0; i < 16; ++i) sQ[t + 512 * i] = Q[t + 512 * i];
    #pragma unroll
    for (int i = 0; i < 16; ++i) sR[t + 512 * i] = R[t + 512 * i];
    if (t < FDIM) swa[t] = Wa[t];
    soh[64 + (t >> 2)][t & 3] = 0.0f;                  // h = 0

    // state role: (row r7, seq sA), f-pairs packed
    const int r7 = t & 127, sA = t >> 7;
    fv2 re2[FDIM / 2], im2[FDIM / 2];
    #pragma unroll
    for (int j = 0; j < FDIM / 2; ++j) { re2[j] = 0.0f; im2[j] = 0.0f; }

    // mogrify roles (R9-verbatim)
    const int mc = t & 63,  mksx = t >> 6;             // x: col mc, 8 k-slices of 16
    const int mj = t & 127, mksh = t >> 7;             // h: col mj, 4 k-slices of 16

    // gate PARTIAL role (t<448): group gg owns cols 4gg..4gg+3, k-slice gks
    const int gks = t / 112, gg = t - gks * 112;
    const int gcol0 = 4 * gg;
    const float* wPt = Wi; int strP = HDIM;
    if      (gcol0 < 128) { wPt = Wi   + gcol0;         strP = HDIM; }
    else if (gcol0 < 256) { wPt = Wg   + (gcol0 - 128); strP = HDIM; }
    else if (gcol0 < 384) { wPt = Wste + (gcol0 - 256); strP = HDIM; }
    else if (gcol0 < 416) { wPt = Wfre + (gcol0 - 384); strP = FDIM; }
    else                  { wPt = Wom  + (gcol0 - 416); strP = FDIM; }
    wPt += (size_t)(48 * gks) * strP;

    // gate REDUCE role (t<448): col = t
    const float* bG = bi; int reg = -1, gcol = 0;
    if      (t < 128) { bG = bi;   gcol = t;       reg = 0; }
    else if (t < 256) { bG = bg;   gcol = t - 128; reg = 1; }
    else if (t < 384) { bG = bste; gcol = t - 256; reg = 2; }
    else if (t < 416) { bG = bfre; gcol = t - 384; reg = 3; }
    else if (t < 448) { bG = bom;  gcol = t - 416; reg = 4; }
    const float gb = (reg >= 0) ? bG[gcol] : 0.0f;

    // out roles: 16 k-slices x 32 col-groups
    const int oks = t >> 5, og = t & 31;
    const float* woPt = Wo + 4 * og + (size_t)(20 * oks) * HDIM;
    const float bo_r = (t < 128) ? bo[t] : 0.0f;

    const float ba0 = ba[0];
    const float* xbase = x + (size_t)blk * 4 * LSEQ * CDIM;
    const int pl = t - 448;                            // prefetch lane (wave 7)

    // prologue: x(ts=0)
    if (t < 256) soh[t & 63][t >> 6] = xbase[((t >> 6) * LSEQ) * CDIM + (t & 63)];
    __syncthreads();

    for (int ts = 0; ts < LSEQ; ++ts) {
        // ---- mogrify x,h,x,h,x (packed pk_fma) ----
        #pragma unroll
        for (int m = 0; m < 5; ++m) {
            if ((m & 1) == 0) {
                const int k0 = mksx * 16;
                fv2 a01 = 0.0f, a23 = 0.0f;
                #pragma unroll
                for (int kk = 0; kk < 16; ++kk) {
                    const float qv = sQ[(k0 + kk) * CDIM + mc];
                    const fv4 h4 = *(const fv4*)&soh[64 + k0 + kk][0];
                    a01 += h4.lo * qv; a23 += h4.hi * qv;
                }
                float* sp = &spart[mksx * 256 + mc * 4];
                *(fv2*)(sp) = a01; *(fv2*)(sp + 2) = a23;
                __syncthreads();
                if (t < 256) {
                    float v = 0.f;
                    #pragma unroll
                    for (int i = 0; i < 8; ++i) v += spart[i * 256 + t];
                    soh[t >> 2][t & 3] = 2.0f * sigf(v) * soh[t >> 2][t & 3];
                }
                __syncthreads();
            } else {
                const int k0 = mksh * 16;
                fv2 a01 = 0.0f, a23 = 0.0f;
                #pragma unroll
                for (int kk = 0; kk < 16; ++kk) {
                    const float rv = sR[(k0 + kk) * HDIM + mj];
                    const fv4 x4 = *(const fv4*)&soh[k0 + kk][0];
                    a01 += x4.lo * rv; a23 += x4.hi * rv;
                }
                float* sp = &spart[mksh * 512 + mj * 4];
                *(fv2*)(sp) = a01; *(fv2*)(sp + 2) = a23;
                __syncthreads();
                {
                    const float v = spart[t] + spart[512 + t] + spart[1024 + t] + spart[1536 + t];
                    soh[64 + (t >> 2)][t & 3] = 2.0f * sigf(v) * soh[64 + (t >> 2)][t & 3];
                }
                __syncthreads();
            }
        }

        // ---- gate partials (t<448): 48 float4 loads, 8 pk_fma each ----
        float xn0 = 0.f, xn1 = 0.f, xn2 = 0.f, xn3 = 0.f;
        if (t < 448) {
            fv2 a0_01 = 0.0f, a0_23 = 0.0f, a1_01 = 0.0f, a1_23 = 0.0f;
            fv2 a2_01 = 0.0f, a2_23 = 0.0f, a3_01 = 0.0f, a3_23 = 0.0f;
            const float* wp = wPt;
            const int kb = 48 * gks;
            #pragma unroll 8
            for (int kk = 0; kk < 48; ++kk) {
                const fv4 w4 = *(const fv4*)wp; wp += strP;
                const fv4 i4 = *(const fv4*)&soh[kb + kk][0];
                const fv2 i01 = i4.lo, i23 = i4.hi;
                a0_01 += i01 * w4.x; a0_23 += i23 * w4.x;
                a1_01 += i01 * w4.y; a1_23 += i23 * w4.y;
                a2_01 += i01 * w4.z; a2_23 += i23 * w4.z;
                a3_01 += i01 * w4.w; a3_23 += i23 * w4.w;
            }
            float* sp = &spart[(gks * 448 + gcol0) * 4];
            *(fv2*)(sp)      = a0_01; *(fv2*)(sp + 2)  = a0_23;
            *(fv2*)(sp + 4)  = a1_01; *(fv2*)(sp + 6)  = a1_23;
            *(fv2*)(sp + 8)  = a2_01; *(fv2*)(sp + 10) = a2_23;
            *(fv2*)(sp + 12) = a3_01; *(fv2*)(sp + 14) = a3_23;
        } else if (ts + 1 < LSEQ) {
            xn0 = xbase[(0 * LSEQ + ts + 1) * CDIM + pl];
            xn1 = xbase[(1 * LSEQ + ts + 1) * CDIM + pl];
            xn2 = xbase[(2 * LSEQ + ts + 1) * CDIM + pl];
            xn3 = xbase[(3 * LSEQ + ts + 1) * CDIM + pl];
        }
        __syncthreads();

        // ---- gate reduce (t<448): col t, 4 seqs ----
        if (reg >= 0) {
            fv2 v01 = 0.0f, v23 = 0.0f;
            #pragma unroll
            for (int ks = 0; ks < 4; ++ks) {
                const float* pp = &spart[(ks * 448 + t) * 4];
                v01 += *(const fv2*)pp; v23 += *(const fv2*)(pp + 2);
            }
            const float v0 = v01.x + gb, v1 = v01.y + gb;
            const float v2 = v23.x + gb, v3 = v23.y + gb;
            if (reg == 4) {
                const float o0 = TWO_PI * sigf(v0), o1 = TWO_PI * sigf(v1);
                const float o2 = TWO_PI * sigf(v2), o3 = TWO_PI * sigf(v3);
                scosv[0][gcol] = __cosf(o0); ssinv[0][gcol] = __sinf(o0);
                scosv[1][gcol] = __cosf(o1); ssinv[1][gcol] = __sinf(o1);
                scosv[2][gcol] = __cosf(o2); ssinv[2][gcol] = __sinf(o2);
                scosv[3][gcol] = __cosf(o3); ssinv[3][gcol] = __sinf(o3);
            } else if (reg == 3) {
                sffre[0][gcol] = sigf(v0); sffre[1][gcol] = sigf(v1);
                sffre[2][gcol] = sigf(v2); sffre[3][gcol] = sigf(v3);
            } else {
                float* d = (reg == 0) ? &sit[0][0] : (reg == 1) ? &schat[0][0] : &sfste[0][0];
                *(fv4*)&d[gcol * 4] = (fv4){sigf(v0), sigf(v1), sigf(v2), sigf(v3)};
            }
        }
        __syncthreads();

        // ---- complex state + amplitude @ Wa -> c_t (f-pairs packed) ----
        {
            const float ic = sit[r7][sA] * schat[r7][sA];
            const float fs = sfste[r7][sA];
            float acc = 0.f;
            #pragma unroll
            for (int j = 0; j < FDIM / 2; ++j) {
                const fv2 fr2 = *(const fv2*)&sffre[sA][2 * j];
                const fv2 cv2 = *(const fv2*)&scosv[sA][2 * j];
                const fv2 sv2 = *(const fv2*)&ssinv[sA][2 * j];
                const fv2 ft2 = fr2 * fs;
                re2[j] = ft2 * re2[j] + cv2 * ic;
                im2[j] = ft2 * im2[j] + sv2 * ic;
                const fv2 m2 = re2[j] * re2[j] + im2[j] * im2[j];
                acc = fmaf(sqrtf(m2.x), swa[2 * j], acc);
                acc = fmaf(sqrtf(m2.y), swa[2 * j + 1], acc);
            }
            soh[192 + r7][sA] = tanh_fast(acc + ba0);
        }
        __syncthreads();

        // ---- out partials: 20 float4 loads, 8 pk_fma each ----
        {
            fv2 a0_01 = 0.0f, a0_23 = 0.0f, a1_01 = 0.0f, a1_23 = 0.0f;
            fv2 a2_01 = 0.0f, a2_23 = 0.0f, a3_01 = 0.0f, a3_23 = 0.0f;
            const float* wp = woPt;
            const int kb = 20 * oks;
            #pragma unroll 5
            for (int kk = 0; kk < 20; ++kk) {
                const fv4 w4 = *(const fv4*)wp; wp += HDIM;
                const fv4 i4 = *(const fv4*)&soh[kb + kk][0];
                const fv2 i01 = i4.lo, i23 = i4.hi;
                a0_01 += i01 * w4.x; a0_23 += i23 * w4.x;
                a1_01 += i01 * w4.y; a1_23 += i23 * w4.y;
                a2_01 += i01 * w4.z; a2_23 += i23 * w4.z;
                a3_01 += i01 * w4.w; a3_23 += i23 * w4.w;
            }
            float* sp = &spart[(oks * 128 + 4 * og) * 4];
            *(fv2*)(sp)      = a0_01; *(fv2*)(sp + 2)  = a0_23;
            *(fv2*)(sp + 4)  = a1_01; *(fv2*)(sp + 6)  = a1_23;
            *(fv2*)(sp + 8)  = a2_01; *(fv2*)(sp + 10) = a2_23;
            *(fv2*)(sp + 12) = a3_01; *(fv2*)(sp + 14) = a3_23;
        }
        __syncthreads();

        // ---- out reduce (t<128) + x commit (wave 7) ----
        if (t < 128) {
            fv2 v01 = 0.0f, v23 = 0.0f;
            #pragma unroll
            for (int ks = 0; ks < 16; ++ks) {
                const float* pp = &spart[(ks * 128 + t) * 4];
                v01 += *(const fv2*)pp; v23 += *(const fv2*)(pp + 2);
            }
            const fv4 ct4 = *(const fv4*)&soh[192 + t][0];
            fv4 h4;
            h4.x = sigf(v01.x + bo_r) * tanh_fast(ct4.x);
            h4.y = sigf(v01.y + bo_r) * tanh_fast(ct4.y);
            h4.z = sigf(v23.x + bo_r) * tanh_fast(ct4.z);
            h4.w = sigf(v23.y + bo_r) * tanh_fast(ct4.w);
            *(fv4*)&soh[64 + t][0] = h4;
        } else if (t >= 448 && ts + 1 < LSEQ) {
            soh[pl][0] = xn0; soh[pl][1] = xn1;
            soh[pl][2] = xn2; soh[pl][3] = xn3;
        }
        __syncthreads();
    }

    // ---- out = h_last @ Wout + bout, one wave per sequence ----
    if (t < 256) {
        const int w = t >> 6, l = t & 63;
        float p = soh[64 + l][w] * Wout[l] + soh[128 + l][w] * Wout[64 + l];
        #pragma unroll
        for (int off = 32; off > 0; off >>= 1) p += __shfl_xor(p, off);
        if (l == 0) out[blk * 4 + w] = p + bout[0];
    }
}

extern "C" void kernel_launch(void* const* d_in, const int* in_sizes, int n_in,
                              void* d_out, int out_size, void* d_ws, size_t ws_size,
                              hipStream_t stream) {
    const float* x    = (const float*)d_in[0];
    const float* Q    = (const float*)d_in[1];
    const float* R    = (const float*)d_in[2];
    const float* Wi   = (const float*)d_in[3];
    const float* bi   = (const float*)d_in[4];
    const float* Wg   = (const float*)d_in[5];
    const float* bg   = (const float*)d_in[6];
    const float* Wste = (const float*)d_in[7];
    const float* bste = (const float*)d_in[8];
    const float* Wfre = (const float*)d_in[9];
    const float* bfre = (const float*)d_in[10];
    const float* Wom  = (const float*)d_in[11];
    const float* bom  = (const float*)d_in[12];
    const float* Wo   = (const float*)d_in[13];
    const float* bo   = (const float*)d_in[14];
    const float* Wa   = (const float*)d_in[15];
    const float* ba   = (const float*)d_in[16];
    const float* Wout = (const float*)d_in[17];
    const float* bout = (const float*)d_in[18];
    float* out = (float*)d_out;

    sfm_lstm_r13<<<dim3(256), dim3(512), 0, stream>>>(
        x, Q, R, Wi, bi, Wg, bg, Wste, bste, Wfre, bfre, Wom, bom,
        Wo, bo, Wa, ba, Wout, bout, out);
}